// Round 8
// baseline (40.835 us; speedup 1.0000x reference)
//
#include <hip/hip_runtime.h>

#define NQ 6
#define NL 6
#define TSTRIDE 148   // words per sample trig row: 36 gates * 4 + 4 pad

// R7 layout: 16 lanes per sample, 4 samples/wave (8192 waves -> 8 waves/SIMD).
// amplitude k = (b5<<5)|(b4<<4)|(b3<<3)|(b2<<2)|(b1<<1)|b0
//   b5 <-> L bit3, b4 <-> L bit2, b3 <-> L bit1, b2 <-> L bit0   (L = lane & 15)
//   b1 = v2f pair index p (re[0],re[1]), b0 = half h (.x/.y)
//   sample-within-wave sw = lane >> 4
// Qubit q <-> amp bit (5-q). Lane shuffles (within a 16-lane row, pure VALU DPP):
//   lane^1 = quad_perm 0xB1, lane^2 = quad_perm 0x4E,
//   lane^4 = ROW_HALF_MIRROR(0x141) o quad_perm 0x1B  (validated R5/R6),
//   lane^8 = ROW_ROR:8 (0x128) — rotation by 8 in a 16-ring == xor 8 (symmetric).

typedef float v2f __attribute__((ext_vector_type(2)));

template<int CTRL>
__device__ __forceinline__ float dppf(float x) {
    return __builtin_bit_cast(float,
        __builtin_amdgcn_update_dpp(0, __builtin_bit_cast(int, x), CTRL, 0xF, 0xF, true));
}
__device__ __forceinline__ float sx1(float x) { return dppf<0xB1>(x); }
__device__ __forceinline__ float sx2(float x) { return dppf<0x4E>(x); }
__device__ __forceinline__ float sx4(float x) { return dppf<0x1B>(dppf<0x141>(x)); }
__device__ __forceinline__ float sx8(float x) { return dppf<0x128>(x); }

__device__ __forceinline__ v2f fma2(v2f a, v2f b, v2f c) {
    return __builtin_elementwise_fma(a, b, c);
}
__device__ __forceinline__ v2f swap2(v2f a) { return __builtin_shufflevector(a, a, 1, 0); }

template<int M>
__device__ __forceinline__ v2f shuf2(v2f a) {
    if constexpr (M == 1) return v2f{sx1(a.x), sx1(a.y)};
    else if constexpr (M == 2) return v2f{sx2(a.x), sx2(a.y)};
    else if constexpr (M == 4) return v2f{sx4(a.x), sx4(a.y)};
    else return v2f{sx8(a.x), sx8(a.y)};
}

// ---- RZ(q): diagonal, no communication ----
template<int Q>
__device__ __forceinline__ void rz2(v2f (&re)[2], v2f (&im)[2], float c, float s, int L) {
    const v2f C = {c, c};
    if constexpr (Q < 4) {                     // lane qubit, mask 8>>Q
        const int lm = 8 >> Q;
        const float s2 = (L & lm) ? s : -s;
        const v2f S = {s2, s2};
        #pragma unroll
        for (int p = 0; p < 2; ++p) {
            const v2f nr = fma2(re[p], C, -(im[p] * S));
            im[p] = fma2(re[p], S, im[p] * C);
            re[p] = nr;
        }
    } else if constexpr (Q == 4) {             // pair qubit: p0 -> -s, p1 -> +s
        const v2f Sn = {-s, -s}, Sp = {s, s};
        { const v2f nr = fma2(re[0], C, -(im[0] * Sn));
          im[0] = fma2(re[0], Sn, im[0] * C); re[0] = nr; }
        { const v2f nr = fma2(re[1], C, -(im[1] * Sp));
          im[1] = fma2(re[1], Sp, im[1] * C); re[1] = nr; }
    } else {                                   // half qubit: S = {-s, +s}
        const v2f S = {-s, s};
        #pragma unroll
        for (int p = 0; p < 2; ++p) {
            const v2f nr = fma2(re[p], C, -(im[p] * S));
            im[p] = fma2(re[p], S, im[p] * C);
            re[p] = nr;
        }
    }
}

// ---- RY(q) ----
template<int Q>
__device__ __forceinline__ void ry2(v2f (&re)[2], v2f (&im)[2], float c, float s, int L) {
    const v2f C = {c, c};
    if constexpr (Q < 4) {                     // lane qubit
        const int lm = 8 >> Q;
        const float sg = (L & lm) ? s : -s;
        const v2f SG = {sg, sg};
        #pragma unroll
        for (int p = 0; p < 2; ++p) {
            const v2f ore = shuf2<(8 >> Q)>(re[p]);
            const v2f oim = shuf2<(8 >> Q)>(im[p]);
            re[p] = fma2(C, re[p], SG * ore);
            im[p] = fma2(C, im[p], SG * oim);
        }
    } else if constexpr (Q == 4) {             // pair butterfly
        const v2f S = {s, s};
        const v2f a0r = re[0], a0i = im[0], a1r = re[1], a1i = im[1];
        re[0] = fma2(C, a0r, -(S * a1r));
        im[0] = fma2(C, a0i, -(S * a1i));
        re[1] = fma2(S, a0r, C * a1r);
        im[1] = fma2(S, a0i, C * a1i);
    } else {                                   // within-pair butterfly
        const v2f SM = {-s, s};
        #pragma unroll
        for (int p = 0; p < 2; ++p) {
            re[p] = fma2(C, re[p], SM * swap2(re[p]));
            im[p] = fma2(C, im[p], SM * swap2(im[p]));
        }
    }
}

__device__ __forceinline__ void cnot_block(v2f (&re)[2], v2f (&im)[2], int L) {
    // CNOT(0,1): ctrl b5 (L&8), tgt b4 (lane^4)
    const bool c01 = (L & 8) != 0;
    #pragma unroll
    for (int p = 0; p < 2; ++p) {
        const v2f dr = shuf2<4>(re[p]), di = shuf2<4>(im[p]);
        re[p] = c01 ? dr : re[p];
        im[p] = c01 ? di : im[p];
    }
    // CNOT(1,2): ctrl b4 (L&4), tgt b3 (lane^2)
    const bool c12 = (L & 4) != 0;
    #pragma unroll
    for (int p = 0; p < 2; ++p) {
        const v2f dr = shuf2<2>(re[p]), di = shuf2<2>(im[p]);
        re[p] = c12 ? dr : re[p];
        im[p] = c12 ? di : im[p];
    }
    // CNOT(2,3): ctrl b3 (L&2), tgt b2 (lane^1)
    const bool c23 = (L & 2) != 0;
    #pragma unroll
    for (int p = 0; p < 2; ++p) {
        const v2f dr = shuf2<1>(re[p]), di = shuf2<1>(im[p]);
        re[p] = c23 ? dr : re[p];
        im[p] = c23 ? di : im[p];
    }
    // CNOT(3,4): ctrl b2 (L&1), tgt b1: conditional pair swap
    const bool c34 = (L & 1) != 0;
    {
        const v2f ar = re[0], ai = im[0], br = re[1], bi = im[1];
        re[0] = c34 ? br : ar;  im[0] = c34 ? bi : ai;
        re[1] = c34 ? ar : br;  im[1] = c34 ? ai : bi;
    }
    // CNOT(4,5): ctrl b1 (pair 1), tgt b0: unconditional half-swap of pair 1
    re[1] = swap2(re[1]);  im[1] = swap2(im[1]);
    // CNOT(5,0): ctrl b0 (.y halves), tgt b5: lane^8 on .y only
    #pragma unroll
    for (int p = 0; p < 2; ++p) {
        re[p].y = sx8(re[p].y);
        im[p].y = sx8(im[p].y);
    }
}

__global__ __launch_bounds__(256, 8) void qsim_kernel(
    const float* __restrict__ x,
    const float* __restrict__ w,
    float* __restrict__ out,
    int batch)
{
    __shared__ float tbl[16 * TSTRIDE];
    __shared__ float outbuf[4][24];

    const int tid   = threadIdx.x;
    const int wavei = tid >> 6;
    const int lane  = tid & 63;
    const int L     = lane & 15;          // position within sample
    const int sw    = lane >> 4;          // sample within wave 0..3
    const int S     = tid >> 4;           // sample within block 0..15
    const int b     = blockIdx.x * 16 + S;
    if (b >= batch) return;               // exact for B=32768 (never divergent)

    float* T = &tbl[S * TSTRIDE];

    // ---- wave-local trig fill: 72 angles/sample, 5 per lane ----
    {
        const float* wp = w + (size_t)b * (2 * NQ * NL);
        #pragma unroll
        for (int j = 0; j < 5; ++j) {
            const int A = L + 16 * j;                     // angle id
            if (A < 72) {
                float s, c;
                __sincosf(wp[A] * 0.5f, &s, &c);
                const int word = (A >> 1) * 4 + (A & 1) * 2;  // gate*4 + {0:z,2:y}
                T[word]     = c;
                T[word + 1] = s;
            }
        }
    }

    // ---- encode: product state amp[k] = A^(6-popc(k)) * B^popc(k) ----
    const float x0 = x[b * 3 + 0];
    const float x1 = x[b * 3 + 1];
    const float x2 = x[b * 3 + 2];
    const float z  = fminf(1.f, fmaxf(-1.f, x2));
    const float ct = sqrtf(0.5f * (1.f + z));
    const float st = sqrtf(0.5f * (1.f - z));
    const float rr = sqrtf(x0 * x0 + x1 * x1) + 1e-30f;
    const float cphi = x0 / rr;
    const float cp = sqrtf(fmaxf(0.f, 0.5f * (1.f + cphi)));
    float sp       = sqrtf(fmaxf(0.f, 0.5f * (1.f - cphi)));
    sp = (x1 < 0.f) ? -sp : sp;   // 2pi wrap & sign = global phase, cancels

    const float Ar = ct * cp, Ai = -ct * sp;
    const float Br = st * cp, Bi =  st * sp;

    float pr[7], pi_[7], qr[7], qi[7];
    pr[0] = 1.f; pi_[0] = 0.f; qr[0] = 1.f; qi[0] = 0.f;
    pr[1] = Ar;  pi_[1] = Ai;  qr[1] = Br;  qi[1] = Bi;
    #pragma unroll
    for (int p = 2; p <= 6; ++p) {
        pr[p]  = fmaf(pr[p-1], Ar, -(pi_[p-1] * Ai));
        pi_[p] = fmaf(pr[p-1], Ai,  pi_[p-1] * Ar);
        qr[p]  = fmaf(qr[p-1], Br, -(qi[p-1] * Bi));
        qi[p]  = fmaf(qr[p-1], Bi,  qi[p-1] * Br);
    }
    float cr[7], ci[7];
    #pragma unroll
    for (int p = 0; p <= 6; ++p) {
        cr[p] = fmaf(pr[6-p], qr[p], -(pi_[6-p] * qi[p]));
        ci[p] = fmaf(pr[6-p], qi[p],  pi_[6-p] * qr[p]);
    }
    // amplitude (L,p,h) has popcount popc(L)+p+h -> need c[pg+j], j=0..2
    const int  pg  = __popc(L);                  // 0..4
    const bool pb0 = (pg & 1) != 0, pb1 = (pg & 2) != 0, pb2 = (pg & 4) != 0;
    float ur[3], ui[3];
    #pragma unroll
    for (int j = 0; j < 3; ++j) {
        const float a01 = pb0 ? cr[j+1] : cr[j];
        const float b01 = pb0 ? ci[j+1] : ci[j];
        const float a23 = pb0 ? cr[j+3] : cr[j+2];
        const float b23 = pb0 ? ci[j+3] : ci[j+2];
        const float lor = pb1 ? a23 : a01;
        const float loi = pb1 ? b23 : b01;
        ur[j] = pb2 ? cr[j+4] : lor;            // pg=4 -> pb0=pb1=0
        ui[j] = pb2 ? ci[j+4] : loi;
    }
    v2f re[2], im[2];
    re[0] = v2f{ur[0], ur[1]};  im[0] = v2f{ui[0], ui[1]};
    re[1] = v2f{ur[1], ur[2]};  im[1] = v2f{ui[1], ui[2]};

    // ---- variational layers ----
    #define LAYER_GATES(l)                                                   \
    do {                                                                     \
        const float4 c0 = *(const float4*)&T[(l)*24 +  0];                   \
        const float4 c1 = *(const float4*)&T[(l)*24 +  4];                   \
        const float4 c2 = *(const float4*)&T[(l)*24 +  8];                   \
        const float4 c3 = *(const float4*)&T[(l)*24 + 12];                   \
        const float4 c4 = *(const float4*)&T[(l)*24 + 16];                   \
        const float4 c5 = *(const float4*)&T[(l)*24 + 20];                   \
        rz2<0>(re, im, c0.x, c0.y, L);  ry2<0>(re, im, c0.z, c0.w, L);       \
        rz2<1>(re, im, c1.x, c1.y, L);  ry2<1>(re, im, c1.z, c1.w, L);       \
        rz2<2>(re, im, c2.x, c2.y, L);  ry2<2>(re, im, c2.z, c2.w, L);       \
        rz2<3>(re, im, c3.x, c3.y, L);  ry2<3>(re, im, c3.z, c3.w, L);       \
        rz2<4>(re, im, c4.x, c4.y, L);  ry2<4>(re, im, c4.z, c4.w, L);       \
        rz2<5>(re, im, c5.x, c5.y, L);  ry2<5>(re, im, c5.z, c5.w, L);       \
    } while (0)

    for (int l = 0; l < NL - 1; ++l) {
        LAYER_GATES(l);
        cnot_block(re, im, L);
    }
    LAYER_GATES(NL - 1);   // final CNOT block folded into readout remap

    // ---- probs -> FWHT (2 register stages + within-pair + 4 lane stages) ----
    v2f v[2];
    v[0] = fma2(re[0], re[0], im[0] * im[0]);
    v[1] = fma2(re[1], re[1], im[1] * im[1]);
    {   // amp bit1 (pair)
        const v2f a = v[0], bb = v[1];
        v[0] = a + bb; v[1] = a - bb;
    }
    {   // amp bit0 (half)
        const v2f PM = {1.f, -1.f};
        v[0] = fma2(PM, v[0], swap2(v[0]));
        v[1] = fma2(PM, v[1], swap2(v[1]));
    }
    {   // amp bit2 <-> L bit0
        const float sg = (L & 1) ? -1.f : 1.f;  const v2f SG = {sg, sg};
        v[0] = fma2(SG, v[0], shuf2<1>(v[0]));
        v[1] = fma2(SG, v[1], shuf2<1>(v[1]));
    }
    {   // amp bit3 <-> L bit1
        const float sg = (L & 2) ? -1.f : 1.f;  const v2f SG = {sg, sg};
        v[0] = fma2(SG, v[0], shuf2<2>(v[0]));
        v[1] = fma2(SG, v[1], shuf2<2>(v[1]));
    }
    {   // amp bit4 <-> L bit2
        const float sg = (L & 4) ? -1.f : 1.f;  const v2f SG = {sg, sg};
        v[0] = fma2(SG, v[0], shuf2<4>(v[0]));
        v[1] = fma2(SG, v[1], shuf2<4>(v[1]));
    }
    {   // amp bit5 <-> L bit3
        const float sg = (L & 8) ? -1.f : 1.f;  const v2f SG = {sg, sg};
        v[0] = fma2(SG, v[0], shuf2<8>(v[0]));
        v[1] = fma2(SG, v[1], shuf2<8>(v[1]));
    }
    // lane L, pair p, half h holds WHT[L*4 + 2p + h]

    // ---- readout (skipped final-CNOT remap, validated): e = {31,48,56,60,62,63} ----
    if (L == 7)  outbuf[wavei][sw * 6 + 0] = v[1].y;   // e=31
    if (L == 12) outbuf[wavei][sw * 6 + 1] = v[0].x;   // e=48
    if (L == 14) outbuf[wavei][sw * 6 + 2] = v[0].x;   // e=56
    if (L == 15) {
        outbuf[wavei][sw * 6 + 3] = v[0].x;            // e=60
        outbuf[wavei][sw * 6 + 4] = v[1].x;            // e=62
        outbuf[wavei][sw * 6 + 5] = v[1].y;            // e=63
    }
    if (lane < 24) {
        const float ev = outbuf[wavei][lane];
        const long long oidx = (long long)(blockIdx.x * 16 + wavei * 4) * 6 + lane;
        if (oidx < (long long)batch * 6)
            out[oidx] = 1.f / (1.f + __expf(-ev));
    }
    #undef LAYER_GATES
}

extern "C" void kernel_launch(void* const* d_in, const int* in_sizes, int n_in,
                              void* d_out, int out_size, void* d_ws, size_t ws_size,
                              hipStream_t stream) {
    const float* x = (const float*)d_in[0];
    const float* w = (const float*)d_in[1];
    float* out = (float*)d_out;
    const int batch = in_sizes[0] / 3;   // B = 32768

    const int threads = 256;             // 4 waves = 16 samples per block
    const int blocks = (batch + 15) / 16;
    qsim_kernel<<<blocks, threads, 0, stream>>>(x, w, out, batch);
}

// Round 9
// 27.844 us; speedup vs baseline: 1.4666x; 1.4666x over previous
//
#include <hip/hip_runtime.h>

#define NQ 6
#define NL 6
#define TSTRIDE 148   // words per sample trig row: 36 gates * 4 + 4 pad (row base 592B = 16B-aligned)

// R9 = R7/R8 layout (validated: passed R8), with gate-based encode to kill spills.
// 16 lanes per sample, 4 samples/wave (8192 waves -> 8 waves/SIMD).
// amplitude k = (b5<<5)|(b4<<4)|(b3<<3)|(b2<<2)|(b1<<1)|b0
//   b5 <-> L bit3, b4 <-> L bit2, b3 <-> L bit1, b2 <-> L bit0   (L = lane & 15)
//   b1 = v2f pair index p (re[0],re[1]), b0 = half h (.x/.y)
// Qubit q <-> amp bit (5-q). Lane shuffles (pure VALU DPP):
//   lane^1 = quad_perm 0xB1, lane^2 = quad_perm 0x4E,
//   lane^4 = ROW_HALF_MIRROR(0x141) o quad_perm 0x1B,
//   lane^8 = ROW_ROR:8 (0x128) — rotation by 8 in 16-ring == xor 8.

typedef float v2f __attribute__((ext_vector_type(2)));

template<int CTRL>
__device__ __forceinline__ float dppf(float x) {
    return __builtin_bit_cast(float,
        __builtin_amdgcn_update_dpp(0, __builtin_bit_cast(int, x), CTRL, 0xF, 0xF, true));
}
__device__ __forceinline__ float sx1(float x) { return dppf<0xB1>(x); }
__device__ __forceinline__ float sx2(float x) { return dppf<0x4E>(x); }
__device__ __forceinline__ float sx4(float x) { return dppf<0x1B>(dppf<0x141>(x)); }
__device__ __forceinline__ float sx8(float x) { return dppf<0x128>(x); }

__device__ __forceinline__ v2f fma2(v2f a, v2f b, v2f c) {
    return __builtin_elementwise_fma(a, b, c);
}
__device__ __forceinline__ v2f swap2(v2f a) { return __builtin_shufflevector(a, a, 1, 0); }

template<int M>
__device__ __forceinline__ v2f shuf2(v2f a) {
    if constexpr (M == 1) return v2f{sx1(a.x), sx1(a.y)};
    else if constexpr (M == 2) return v2f{sx2(a.x), sx2(a.y)};
    else if constexpr (M == 4) return v2f{sx4(a.x), sx4(a.y)};
    else return v2f{sx8(a.x), sx8(a.y)};
}

// ---- RZ(q): diagonal, no communication ----
template<int Q>
__device__ __forceinline__ void rz2(v2f (&re)[2], v2f (&im)[2], float c, float s, int L) {
    const v2f C = {c, c};
    if constexpr (Q < 4) {
        const int lm = 8 >> Q;
        const float s2 = (L & lm) ? s : -s;
        const v2f S = {s2, s2};
        #pragma unroll
        for (int p = 0; p < 2; ++p) {
            const v2f nr = fma2(re[p], C, -(im[p] * S));
            im[p] = fma2(re[p], S, im[p] * C);
            re[p] = nr;
        }
    } else if constexpr (Q == 4) {
        const v2f Sn = {-s, -s}, Sp = {s, s};
        { const v2f nr = fma2(re[0], C, -(im[0] * Sn));
          im[0] = fma2(re[0], Sn, im[0] * C); re[0] = nr; }
        { const v2f nr = fma2(re[1], C, -(im[1] * Sp));
          im[1] = fma2(re[1], Sp, im[1] * C); re[1] = nr; }
    } else {
        const v2f S = {-s, s};
        #pragma unroll
        for (int p = 0; p < 2; ++p) {
            const v2f nr = fma2(re[p], C, -(im[p] * S));
            im[p] = fma2(re[p], S, im[p] * C);
            re[p] = nr;
        }
    }
}

// ---- RY(q) ----
template<int Q>
__device__ __forceinline__ void ry2(v2f (&re)[2], v2f (&im)[2], float c, float s, int L) {
    const v2f C = {c, c};
    if constexpr (Q < 4) {
        const int lm = 8 >> Q;
        const float sg = (L & lm) ? s : -s;
        const v2f SG = {sg, sg};
        #pragma unroll
        for (int p = 0; p < 2; ++p) {
            const v2f ore = shuf2<(8 >> Q)>(re[p]);
            const v2f oim = shuf2<(8 >> Q)>(im[p]);
            re[p] = fma2(C, re[p], SG * ore);
            im[p] = fma2(C, im[p], SG * oim);
        }
    } else if constexpr (Q == 4) {
        const v2f S = {s, s};
        const v2f a0r = re[0], a0i = im[0], a1r = re[1], a1i = im[1];
        re[0] = fma2(C, a0r, -(S * a1r));
        im[0] = fma2(C, a0i, -(S * a1i));
        re[1] = fma2(S, a0r, C * a1r);
        im[1] = fma2(S, a0i, C * a1i);
    } else {
        const v2f SM = {-s, s};
        #pragma unroll
        for (int p = 0; p < 2; ++p) {
            re[p] = fma2(C, re[p], SM * swap2(re[p]));
            im[p] = fma2(C, im[p], SM * swap2(im[p]));
        }
    }
}

__device__ __forceinline__ void cnot_block(v2f (&re)[2], v2f (&im)[2], int L) {
    // CNOT(0,1): ctrl b5 (L&8), tgt b4 (lane^4)
    const bool c01 = (L & 8) != 0;
    #pragma unroll
    for (int p = 0; p < 2; ++p) {
        const v2f dr = shuf2<4>(re[p]), di = shuf2<4>(im[p]);
        re[p] = c01 ? dr : re[p];
        im[p] = c01 ? di : im[p];
    }
    // CNOT(1,2): ctrl b4 (L&4), tgt b3 (lane^2)
    const bool c12 = (L & 4) != 0;
    #pragma unroll
    for (int p = 0; p < 2; ++p) {
        const v2f dr = shuf2<2>(re[p]), di = shuf2<2>(im[p]);
        re[p] = c12 ? dr : re[p];
        im[p] = c12 ? di : im[p];
    }
    // CNOT(2,3): ctrl b3 (L&2), tgt b2 (lane^1)
    const bool c23 = (L & 2) != 0;
    #pragma unroll
    for (int p = 0; p < 2; ++p) {
        const v2f dr = shuf2<1>(re[p]), di = shuf2<1>(im[p]);
        re[p] = c23 ? dr : re[p];
        im[p] = c23 ? di : im[p];
    }
    // CNOT(3,4): ctrl b2 (L&1), tgt b1: conditional pair swap
    const bool c34 = (L & 1) != 0;
    {
        const v2f ar = re[0], ai = im[0], br = re[1], bi = im[1];
        re[0] = c34 ? br : ar;  im[0] = c34 ? bi : ai;
        re[1] = c34 ? ar : br;  im[1] = c34 ? ai : bi;
    }
    // CNOT(4,5): ctrl b1 (pair 1), tgt b0: unconditional half-swap of pair 1
    re[1] = swap2(re[1]);  im[1] = swap2(im[1]);
    // CNOT(5,0): ctrl b0 (.y halves), tgt b5: lane^8 on .y only
    #pragma unroll
    for (int p = 0; p < 2; ++p) {
        re[p].y = sx8(re[p].y);
        im[p].y = sx8(im[p].y);
    }
}

__global__ __launch_bounds__(256, 8) void qsim_kernel(
    const float* __restrict__ x,
    const float* __restrict__ w,
    float* __restrict__ out,
    int batch)
{
    __shared__ float tbl[16 * TSTRIDE];
    __shared__ float outbuf[4][24];

    const int tid   = threadIdx.x;
    const int wavei = tid >> 6;
    const int lane  = tid & 63;
    const int L     = lane & 15;          // position within sample
    const int sw    = lane >> 4;          // sample within wave 0..3
    const int S     = tid >> 4;           // sample within block 0..15
    const int b     = blockIdx.x * 16 + S;
    if (b >= batch) return;               // exact for B=32768 (never divergent)

    float* T = &tbl[S * TSTRIDE];

    // ---- wave-local trig fill: 72 angles/sample, <=5 per lane ----
    {
        const float* wp = w + (size_t)b * (2 * NQ * NL);
        #pragma unroll
        for (int j = 0; j < 5; ++j) {
            const int A = L + 16 * j;                     // angle id
            if (A < 72) {
                float s, c;
                __sincosf(wp[A] * 0.5f, &s, &c);
                const int word = (A >> 1) * 4 + (A & 1) * 2;  // gate*4 + {0:z,2:y}
                T[word]     = c;
                T[word + 1] = s;
            }
        }
    }

    // ---- encode angles via half-angle identities (4 live scalars, no arrays) ----
    const float x0 = x[b * 3 + 0];
    const float x1 = x[b * 3 + 1];
    const float x2 = x[b * 3 + 2];
    const float z  = fminf(1.f, fmaxf(-1.f, x2));
    const float ct = sqrtf(0.5f * (1.f + z));             // cos(theta/2)
    const float st = sqrtf(0.5f * (1.f - z));             // sin(theta/2)
    const float rr = sqrtf(x0 * x0 + x1 * x1) + 1e-30f;
    const float cphi = x0 / rr;
    const float cp = sqrtf(fmaxf(0.f, 0.5f * (1.f + cphi)));
    float sp       = sqrtf(fmaxf(0.f, 0.5f * (1.f - cphi)));
    sp = (x1 < 0.f) ? -sp : sp;   // 2pi wrap & sign = global phase, cancels

    // ---- |0...0> then gate-based encode: RY(theta), RZ(phi) per qubit ----
    v2f re[2], im[2];
    re[0] = v2f{(L == 0) ? 1.f : 0.f, 0.f};
    re[1] = v2f{0.f, 0.f};
    im[0] = v2f{0.f, 0.f};
    im[1] = v2f{0.f, 0.f};

    ry2<0>(re, im, ct, st, L);  rz2<0>(re, im, cp, sp, L);
    ry2<1>(re, im, ct, st, L);  rz2<1>(re, im, cp, sp, L);
    ry2<2>(re, im, ct, st, L);  rz2<2>(re, im, cp, sp, L);
    ry2<3>(re, im, ct, st, L);  rz2<3>(re, im, cp, sp, L);
    ry2<4>(re, im, ct, st, L);  rz2<4>(re, im, cp, sp, L);
    ry2<5>(re, im, ct, st, L);  rz2<5>(re, im, cp, sp, L);

    // ---- variational layers ----
    #define LAYER_GATES(l)                                                   \
    do {                                                                     \
        const float4 c0 = *(const float4*)&T[(l)*24 +  0];                   \
        const float4 c1 = *(const float4*)&T[(l)*24 +  4];                   \
        const float4 c2 = *(const float4*)&T[(l)*24 +  8];                   \
        const float4 c3 = *(const float4*)&T[(l)*24 + 12];                   \
        const float4 c4 = *(const float4*)&T[(l)*24 + 16];                   \
        const float4 c5 = *(const float4*)&T[(l)*24 + 20];                   \
        rz2<0>(re, im, c0.x, c0.y, L);  ry2<0>(re, im, c0.z, c0.w, L);       \
        rz2<1>(re, im, c1.x, c1.y, L);  ry2<1>(re, im, c1.z, c1.w, L);       \
        rz2<2>(re, im, c2.x, c2.y, L);  ry2<2>(re, im, c2.z, c2.w, L);       \
        rz2<3>(re, im, c3.x, c3.y, L);  ry2<3>(re, im, c3.z, c3.w, L);       \
        rz2<4>(re, im, c4.x, c4.y, L);  ry2<4>(re, im, c4.z, c4.w, L);       \
        rz2<5>(re, im, c5.x, c5.y, L);  ry2<5>(re, im, c5.z, c5.w, L);       \
    } while (0)

    for (int l = 0; l < NL - 1; ++l) {
        LAYER_GATES(l);
        cnot_block(re, im, L);
    }
    LAYER_GATES(NL - 1);   // final CNOT block folded into readout remap

    // ---- probs -> FWHT (2 register stages + 4 lane stages) ----
    v2f v[2];
    v[0] = fma2(re[0], re[0], im[0] * im[0]);
    v[1] = fma2(re[1], re[1], im[1] * im[1]);
    {   // amp bit1 (pair)
        const v2f a = v[0], bb = v[1];
        v[0] = a + bb; v[1] = a - bb;
    }
    {   // amp bit0 (half)
        const v2f PM = {1.f, -1.f};
        v[0] = fma2(PM, v[0], swap2(v[0]));
        v[1] = fma2(PM, v[1], swap2(v[1]));
    }
    {   // amp bit2 <-> L bit0
        const float sg = (L & 1) ? -1.f : 1.f;  const v2f SG = {sg, sg};
        v[0] = fma2(SG, v[0], shuf2<1>(v[0]));
        v[1] = fma2(SG, v[1], shuf2<1>(v[1]));
    }
    {   // amp bit3 <-> L bit1
        const float sg = (L & 2) ? -1.f : 1.f;  const v2f SG = {sg, sg};
        v[0] = fma2(SG, v[0], shuf2<2>(v[0]));
        v[1] = fma2(SG, v[1], shuf2<2>(v[1]));
    }
    {   // amp bit4 <-> L bit2
        const float sg = (L & 4) ? -1.f : 1.f;  const v2f SG = {sg, sg};
        v[0] = fma2(SG, v[0], shuf2<4>(v[0]));
        v[1] = fma2(SG, v[1], shuf2<4>(v[1]));
    }
    {   // amp bit5 <-> L bit3
        const float sg = (L & 8) ? -1.f : 1.f;  const v2f SG = {sg, sg};
        v[0] = fma2(SG, v[0], shuf2<8>(v[0]));
        v[1] = fma2(SG, v[1], shuf2<8>(v[1]));
    }
    // lane L, pair p, half h holds WHT[L*4 + 2p + h]

    // ---- readout (skipped final-CNOT remap, validated): e = {31,48,56,60,62,63} ----
    if (L == 7)  outbuf[wavei][sw * 6 + 0] = v[1].y;   // e=31
    if (L == 12) outbuf[wavei][sw * 6 + 1] = v[0].x;   // e=48
    if (L == 14) outbuf[wavei][sw * 6 + 2] = v[0].x;   // e=56
    if (L == 15) {
        outbuf[wavei][sw * 6 + 3] = v[0].x;            // e=60
        outbuf[wavei][sw * 6 + 4] = v[1].x;            // e=62
        outbuf[wavei][sw * 6 + 5] = v[1].y;            // e=63
    }
    if (lane < 24) {
        const float ev = outbuf[wavei][lane];
        const long long oidx = (long long)(blockIdx.x * 16 + wavei * 4) * 6 + lane;
        if (oidx < (long long)batch * 6)
            out[oidx] = 1.f / (1.f + __expf(-ev));
    }
    #undef LAYER_GATES
}

extern "C" void kernel_launch(void* const* d_in, const int* in_sizes, int n_in,
                              void* d_out, int out_size, void* d_ws, size_t ws_size,
                              hipStream_t stream) {
    const float* x = (const float*)d_in[0];
    const float* w = (const float*)d_in[1];
    float* out = (float*)d_out;
    const int batch = in_sizes[0] / 3;   // B = 32768

    const int threads = 256;             // 4 waves = 16 samples per block
    const int blocks = (batch + 15) / 16;
    qsim_kernel<<<blocks, threads, 0, stream>>>(x, w, out, batch);
}